// Round 1
// 993.572 us; speedup vs baseline: 1.1462x; 1.1462x over previous
//
#include <hip/hip_runtime.h>

// ---------------------------------------------------------------------------
// GRU (T=128, N=512, IN=512, H=512) + LayerNorm, MI355X/gfx950.
//   prep:    cast W_hh, W_ih -> bf16, zero barrier flags
//   xconv:   cast half of x -> bf16 (chunked x2 to fit 256 MiB workspace)
//   gi_gemm_bf16: gi = bf16( x @ W_ih^T + b_ih (+ b_hh for r,z) )
//            m97 structure: global_load_lds width-16 staging, 128x128 tile
//            (old f32-staging gemm kept as fallback if ws too small)
//   rec:     128 blocks x 384 thr (32 envs x 64 cols each), W_hh slice in
//            VGPRs, h exchange via global_load_lds (sc0|sc1) + per-group
//            flag barrier (fan-in 8). This round:
//              - gi/mask prefetch double-buffered across steps (S1 no longer
//                drains HBM-latency loads, only the LLC h-DMA)
//              - MFMA split into 2 accumulator chains (halve dep latency)
//              - out f32 stores moved after the flag store (overlap poll)
//              - launch_bounds(384,1): ~210 VGPR without spills; 128 blocks
//                on 256 CUs are resident regardless.
//   ln:      row-wise LayerNorm in-place on d_out
// ---------------------------------------------------------------------------

typedef __attribute__((ext_vector_type(8))) __bf16 bf16x8;
typedef __attribute__((ext_vector_type(4)))  float f32x4;
typedef __attribute__((ext_vector_type(16))) float f32x16;

__device__ __forceinline__ unsigned short f2bf(float f) {
  unsigned u = __builtin_bit_cast(unsigned, f);
  u += 0x7FFFu + ((u >> 16) & 1u);               // RNE
  return (unsigned short)(u >> 16);
}
__device__ __forceinline__ float bf2f(unsigned short h) {
  unsigned u = ((unsigned)h) << 16;
  return __builtin_bit_cast(float, u);
}
__device__ __forceinline__ float sigm(float x) { return 1.0f / (1.0f + __expf(-x)); }
__device__ __forceinline__ float tanh_fast(float x) {
  float t = __expf(2.0f * x);                    // +inf -> 1, 0 -> -1, no NaN
  return 1.0f - 2.0f / (t + 1.0f);
}

// ws layout (bytes)
#define GI_BYTES    ((size_t)65536 * 1536 * 2)          // 201326592
#define WHH_OFF     GI_BYTES
#define WHH_BYTES   ((size_t)1536 * 512 * 2)            // 1572864
#define HB_OFF      (WHH_OFF + WHH_BYTES)
#define HB_BYTES    ((size_t)2 * 512 * 512 * 2)         // 1048576
#define CNT_OFF     (HB_OFF + HB_BYTES)
#define CNT_BYTES   ((size_t)8192)
#define XBF_OFF     (CNT_OFF + CNT_BYTES)
#define XBF_BYTES   ((size_t)32768 * 512 * 2)           // 33554432 (one chunk)
#define WIHBF_OFF   (XBF_OFF + XBF_BYTES)
#define WIHBF_BYTES ((size_t)1536 * 512 * 2)
#define WS_FAST     (WIHBF_OFF + WIHBF_BYTES)           // ~239 MB

// ---------------------------------------------------------------------------
__global__ __launch_bounds__(256) void prep_kernel(const float* __restrict__ whh,
                                                   const float* __restrict__ wih,
                                                   unsigned short* __restrict__ whh_bf,
                                                   unsigned short* __restrict__ wih_bf,
                                                   unsigned int* __restrict__ cnt,
                                                   int fast) {
  int i = blockIdx.x * 256 + threadIdx.x;
  for (int j = i; j < 1536 * 512; j += 1024 * 256) {
    whh_bf[j] = f2bf(whh[j]);
    if (fast) wih_bf[j] = f2bf(wih[j]);
  }
  if (i < 2048) cnt[i] = 0u;      // 128 flags, 64B apart
}

// ---------------------------------------------------------------------------
// Convert 32768x512 f32 chunk of x -> bf16 (4,194,304 float4s).
__global__ __launch_bounds__(256) void xconv_kernel(const float* __restrict__ xsrc,
                                                    unsigned short* __restrict__ xbf) {
  int i = blockIdx.x * 256 + threadIdx.x;          // 4096 blocks -> 1,048,576 thr
  for (int j = i; j < 4194304; j += 1048576) {
    float4 v = *((const float4*)xsrc + j);
    ushort4 o;
    o.x = f2bf(v.x); o.y = f2bf(v.y); o.z = f2bf(v.z); o.w = f2bf(v.w);
    *((ushort4*)xbf + j) = o;
  }
}

// ---------------------------------------------------------------------------
// Fast gi GEMM: C[32768 x 1536] = xbf @ wihbf^T per chunk, 128x128 tiles,
// BK=64, global_load_lds width-16 staging (m97 structure).
__global__ __launch_bounds__(256) void gi_gemm_bf16(const unsigned short* __restrict__ xbf,
                                                    const unsigned short* __restrict__ wihbf,
                                                    const float* __restrict__ bih,
                                                    const float* __restrict__ bhh,
                                                    unsigned short* __restrict__ gi,
                                                    int r0) {
  __shared__ unsigned short As[128 * 64];
  __shared__ unsigned short Bs[128 * 64];
  const int tid = threadIdx.x;
  const int rb = blockIdx.x * 128;
  const int jb = blockIdx.y * 128;
  const int wave = tid >> 6, lane = tid & 63;
  const int wm = wave >> 1, wn = wave & 1;
  const int quad = lane >> 4, l16 = lane & 15;

  f32x4 acc[4][4];
  const f32x4 zero4 = {0.f, 0.f, 0.f, 0.f};
  for (int a = 0; a < 4; ++a)
    for (int b = 0; b < 4; ++b) acc[a][b] = zero4;

  for (int kb = 0; kb < 512; kb += 64) {
    __syncthreads();
#pragma unroll
    for (int r = 0; r < 4; ++r) {
      const int fbase = (r * 256 + wave * 64) * 8;   // wave-uniform elem base
      const int f = fbase + lane * 8;                // per-lane elem idx
      const int row = f >> 6, col = f & 63;
      __builtin_amdgcn_global_load_lds(
          (const __attribute__((address_space(1))) unsigned*)
              (xbf + (size_t)(rb + row) * 512 + kb + col),
          (__attribute__((address_space(3))) unsigned*)(As + fbase), 16, 0, 0);
      __builtin_amdgcn_global_load_lds(
          (const __attribute__((address_space(1))) unsigned*)
              (wihbf + (size_t)(jb + row) * 512 + kb + col),
          (__attribute__((address_space(3))) unsigned*)(Bs + fbase), 16, 0, 0);
    }
    __syncthreads();   // drains LDS-DMA (vmcnt 0)
#pragma unroll
    for (int kk = 0; kk < 64; kk += 32) {
      bf16x8 af[4], bfr[4];
#pragma unroll
      for (int mi = 0; mi < 4; ++mi)
        af[mi] = *(const bf16x8*)(As + (wm * 64 + mi * 16 + l16) * 64 + kk + quad * 8);
#pragma unroll
      for (int ni = 0; ni < 4; ++ni)
        bfr[ni] = *(const bf16x8*)(Bs + (wn * 64 + ni * 16 + l16) * 64 + kk + quad * 8);
#pragma unroll
      for (int mi = 0; mi < 4; ++mi)
#pragma unroll
        for (int ni = 0; ni < 4; ++ni)
          acc[mi][ni] = __builtin_amdgcn_mfma_f32_16x16x32_bf16(af[mi], bfr[ni],
                                                                acc[mi][ni], 0, 0, 0);
    }
  }
#pragma unroll
  for (int ni = 0; ni < 4; ++ni) {
    int jcol = jb + wn * 64 + ni * 16 + l16;
    float bias = bih[jcol] + (jcol < 1024 ? bhh[jcol] : 0.0f);
#pragma unroll
    for (int mi = 0; mi < 4; ++mi) {
#pragma unroll
      for (int reg = 0; reg < 4; ++reg) {
        int grow = r0 + rb + wm * 64 + mi * 16 + quad * 4 + reg;
        gi[(size_t)grow * 1536 + jcol] = f2bf(acc[mi][ni][reg] + bias);
      }
    }
  }
}

// ---------------------------------------------------------------------------
// Fallback gi GEMM (f32 inputs, inline conversion) — used if ws too small.
__global__ __launch_bounds__(256) void gi_gemm_f32(const float* __restrict__ x,
                                                   const float* __restrict__ wih,
                                                   const float* __restrict__ bih,
                                                   const float* __restrict__ bhh,
                                                   unsigned short* __restrict__ gi) {
  __shared__ unsigned short As[128 * 72];
  __shared__ unsigned short Bs[128 * 72];
  const int tid = threadIdx.x;
  const int rb = blockIdx.x * 128;
  const int jb = blockIdx.y * 128;
  const int wave = tid >> 6, lane = tid & 63;
  const int wm = wave >> 1, wn = wave & 1;
  const int quad = lane >> 4, l16 = lane & 15;

  f32x4 acc[4][4];
  const f32x4 zero4 = {0.f, 0.f, 0.f, 0.f};
  for (int a = 0; a < 4; ++a)
    for (int b = 0; b < 4; ++b) acc[a][b] = zero4;

  for (int kb = 0; kb < 512; kb += 64) {
    __syncthreads();
#pragma unroll
    for (int j = 0; j < 8; ++j) {
      int f = tid * 4 + j * 1024;
      int r = f >> 6, k = f & 63;
      float4 av = *(const float4*)(x + (size_t)(rb + r) * 512 + kb + k);
      ushort4 a4;
      a4.x = f2bf(av.x); a4.y = f2bf(av.y); a4.z = f2bf(av.z); a4.w = f2bf(av.w);
      *(ushort4*)(As + r * 72 + k) = a4;
      float4 bv = *(const float4*)(wih + (size_t)(jb + r) * 512 + kb + k);
      ushort4 b4;
      b4.x = f2bf(bv.x); b4.y = f2bf(bv.y); b4.z = f2bf(bv.z); b4.w = f2bf(bv.w);
      *(ushort4*)(Bs + r * 72 + k) = b4;
    }
    __syncthreads();
#pragma unroll
    for (int kk = 0; kk < 64; kk += 32) {
      bf16x8 af[4], bfr[4];
#pragma unroll
      for (int mi = 0; mi < 4; ++mi)
        af[mi] = *(const bf16x8*)(As + (wm * 64 + mi * 16 + l16) * 72 + kk + quad * 8);
#pragma unroll
      for (int ni = 0; ni < 4; ++ni)
        bfr[ni] = *(const bf16x8*)(Bs + (wn * 64 + ni * 16 + l16) * 72 + kk + quad * 8);
#pragma unroll
      for (int mi = 0; mi < 4; ++mi)
#pragma unroll
        for (int ni = 0; ni < 4; ++ni)
          acc[mi][ni] = __builtin_amdgcn_mfma_f32_16x16x32_bf16(af[mi], bfr[ni],
                                                                acc[mi][ni], 0, 0, 0);
    }
  }
#pragma unroll
  for (int ni = 0; ni < 4; ++ni) {
    int jcol = jb + wn * 64 + ni * 16 + l16;
    float bias = bih[jcol] + (jcol < 1024 ? bhh[jcol] : 0.0f);
#pragma unroll
    for (int mi = 0; mi < 4; ++mi) {
#pragma unroll
      for (int reg = 0; reg < 4; ++reg) {
        int grow = rb + wm * 64 + mi * 16 + quad * 4 + reg;
        gi[(size_t)grow * 1536 + jcol] = f2bf(acc[mi][ni][reg] + bias);
      }
    }
  }
}

// ---------------------------------------------------------------------------
// Recurrent kernel: 128 blocks x 384 threads. Block (g = bid>>3, c = bid&7):
// envs [32g,32g+32), h-cols [64c,64c+64). 6 waves: gate = w>>1, half = w&1,
// each wave computes 32 envs x 32 cols via 32x32x16 MFMA, W slice in VGPRs.
#define HL_STRIDE 520          // bf16 elems; 1040 B rows = odd multiple of 16B

// One time step. GRc.. = register set holding THIS step's gi/mask (loaded
// last step); GRn.. = set being prefetched for T+1. HSRC/HDST are u32-unit
// offsets into the ping-pong h buffer. Constant per macro expansion (manual
// 2x unroll keeps all register-array indices compile-time — rule #20).
#define REC_STEP(T, HSRC, HDST, GRc, GZc, GNc, MKc, GRn, GZn, GNn, MKn)        \
  {                                                                            \
    for (int e = wave; e < 32; e += 6) {                                       \
      const unsigned* gp = hbu + (HSRC) + ((unsigned)(eb + e) << 8) + (lane << 2); \
      __builtin_amdgcn_global_load_lds(                                        \
          (const __attribute__((address_space(1))) unsigned*)gp,               \
          (__attribute__((address_space(3))) unsigned*)(Hl + e * HL_STRIDE),   \
          16, 0, 17);                                                          \
    }                                                                          \
    __syncthreads();   /* S1: Hl ready (drains LLC DMA only) */                \
    if ((T) < 127) {                                                           \
      _Pragma("unroll")                                                        \
      for (int j = 0; j < 3; ++j) {                                            \
        int idx = tid + j * 384;                                               \
        if (idx < 1024) {                                                      \
          int e = idx >> 5, cp = (idx & 31) << 1;                              \
          const unsigned short* gp2 =                                          \
              gi + ((size_t)(((T) + 1) * 512 + eb + e) * 1536 + cb + cp);      \
          GRn[j] = *(const unsigned*)gp2;                                      \
          GZn[j] = *(const unsigned*)(gp2 + 512);                              \
          GNn[j] = *(const unsigned*)(gp2 + 1024);                             \
          MKn[j] = masks[((T) + 1) * 512 + eb + e];                            \
        }                                                                      \
      }                                                                        \
    }                                                                          \
    /* gh = Hl(32x512) @ Wslice^T — two interleaved acc chains */              \
    f32x16 acc0 = zeroacc, acc1 = zeroacc;                                     \
    {                                                                          \
      const unsigned short* ap = Hl + l32 * HL_STRIDE + lhi * 8;               \
      _Pragma("unroll")                                                        \
      for (int ks = 0; ks < 32; ks += 2) {                                     \
        bf16x8 a0 = *(const bf16x8*)(ap + (ks << 4));                          \
        bf16x8 a1 = *(const bf16x8*)(ap + ((ks + 1) << 4));                    \
        acc0 = __builtin_amdgcn_mfma_f32_32x32x16_bf16(a0, wreg[ks], acc0, 0, 0, 0); \
        acc1 = __builtin_amdgcn_mfma_f32_32x32x16_bf16(a1, wreg[ks + 1], acc1, 0, 0, 0); \
      }                                                                        \
    }                                                                          \
    {                                                                          \
      float* gt = gatesL + gate * 2048 + half * 32;                            \
      _Pragma("unroll")                                                        \
      for (int reg = 0; reg < 16; ++reg) {                                     \
        int erow = (reg & 3) + 8 * (reg >> 2) + 4 * lhi;                       \
        gt[erow * 64 + l32] = acc0[reg] + acc1[reg];                           \
      }                                                                        \
    }                                                                          \
    __syncthreads();   /* S2: gatesL ready */                                  \
    _Pragma("unroll")                                                          \
    for (int j = 0; j < 3; ++j) {                                              \
      int idx = tid + j * 384;                                                 \
      if (idx < 1024) {                                                        \
        int e = idx >> 5, cp = (idx & 31) << 1;                                \
        float m = MKc[j];                                                      \
        int o = e * 64 + cp;                                                   \
        float r0 = sigm(bf2f((unsigned short)GRc[j]) + m * gatesL[o]);         \
        float r1 = sigm(bf2f((unsigned short)(GRc[j] >> 16)) + m * gatesL[o + 1]); \
        float z0 = sigm(bf2f((unsigned short)GZc[j]) + m * gatesL[2048 + o]);  \
        float z1 = sigm(bf2f((unsigned short)(GZc[j] >> 16)) + m * gatesL[2048 + o + 1]); \
        float n0 = tanh_fast(bf2f((unsigned short)GNc[j]) +                    \
                             r0 * (m * gatesL[4096 + o] + bn0[j]));            \
        float n1 = tanh_fast(bf2f((unsigned short)(GNc[j] >> 16)) +            \
                             r1 * (m * gatesL[4096 + o + 1] + bn1[j]));        \
        float h0 = hr0[j] * m;                                                 \
        float h1 = hr1[j] * m;                                                 \
        float hn0 = (1.0f - z0) * n0 + z0 * h0;                                \
        float hn1 = (1.0f - z1) * n1 + z1 * h1;                                \
        hr0[j] = hn0; hr1[j] = hn1;                                            \
        unsigned pk = (unsigned)f2bf(hn0) | ((unsigned)f2bf(hn1) << 16);       \
        __hip_atomic_store(hbu + (HDST) + ((((unsigned)(eb + e) << 9) + cb + cp) >> 1), \
                           pk, __ATOMIC_RELAXED, __HIP_MEMORY_SCOPE_AGENT);    \
      }                                                                        \
    }                                                                          \
    __syncthreads();   /* S3: drains h publishes (out not yet issued) */       \
    bt += 1;                                                                   \
    if (tid == 0)                                                              \
      __hip_atomic_store(myflag, bt, __ATOMIC_RELAXED, __HIP_MEMORY_SCOPE_AGENT); \
    /* out f32 stores issued now — HBM-write ack overlaps the flag poll */     \
    _Pragma("unroll")                                                          \
    for (int j = 0; j < 3; ++j) {                                              \
      int idx = tid + j * 384;                                                 \
      if (idx < 1024) {                                                        \
        int e = idx >> 5, cp = (idx & 31) << 1;                                \
        float2 ov; ov.x = hr0[j]; ov.y = hr1[j];                               \
        *(float2*)(out + ((size_t)((T) * 512 + eb + e)) * 512 + cb + cp) = ov; \
        if ((T) == 127)                                                        \
          *(float2*)(out + (size_t)33554432 + (size_t)(eb + e) * 512 + cb + cp) = ov; \
      }                                                                        \
    }                                                                          \
    if (tid < 64) {                                                            \
      unsigned int* fp = pollbase + (lane & 7) * 16;                           \
      int guard = 0;                                                           \
      for (;;) {                                                               \
        unsigned v = __hip_atomic_load(fp, __ATOMIC_RELAXED,                   \
                                       __HIP_MEMORY_SCOPE_AGENT);              \
        if (__all(v >= bt)) break;                                             \
        __builtin_amdgcn_s_sleep(1);                                           \
        if (++guard > (1 << 20)) break;                                        \
      }                                                                        \
    }                                                                          \
    __syncthreads();   /* S4: release */                                       \
  }

__global__ __launch_bounds__(384, 1) void rec_kernel(
    const float* __restrict__ hxs, const float* __restrict__ masks,
    const float* __restrict__ bhh, const unsigned short* __restrict__ gi,
    const unsigned short* __restrict__ whh_bf,
    unsigned short* hb, unsigned int* cnt, float* __restrict__ out) {
  __shared__ unsigned short Hl[32 * HL_STRIDE];   // 33280 B
  __shared__ float gatesL[3 * 32 * 64];           // 24576 B

  const int tid = threadIdx.x;
  const int bid = blockIdx.x;
  const int g = bid >> 3;
  const int eb = g * 32;
  const int cb = (bid & 7) * 64;
  const int wave = tid >> 6;          // 0..5
  const int lane = tid & 63;
  const int l32 = lane & 31;
  const int lhi = lane >> 5;
  const int gate = wave >> 1;         // 0(r) 1(z) 2(n)
  const int half = wave & 1;          // col half within 64
  unsigned* hbu = (unsigned*)hb;

  const f32x16 zeroacc = {0.f, 0.f, 0.f, 0.f, 0.f, 0.f, 0.f, 0.f,
                          0.f, 0.f, 0.f, 0.f, 0.f, 0.f, 0.f, 0.f};

  // W_hh slice -> VGPRs: wave's rows = gate*512 + cb + half*32 + l32, K=512
  bf16x8 wreg[32];
  {
    const unsigned short* wb =
        whh_bf + (((size_t)(gate * 512 + cb + half * 32 + l32)) << 9) + lhi * 8;
#pragma unroll
    for (int ks = 0; ks < 32; ++ks) wreg[ks] = *(const bf16x8*)(wb + (ks << 4));
  }

  // own-h registers + loop-invariant b_hh_n prefetch; publish h0 (bf16)
  float hr0[3], hr1[3];
  float bn0[3], bn1[3];
#pragma unroll
  for (int j = 0; j < 3; ++j) {
    int idx = tid + j * 384;
    if (idx < 1024) {
      int e = idx >> 5, cp = (idx & 31) << 1;
      float2 h2 = *(const float2*)(hxs + (size_t)(eb + e) * 512 + cb + cp);
      hr0[j] = h2.x; hr1[j] = h2.y;
      float2 bn2 = *(const float2*)(bhh + 1024 + cb + cp);
      bn0[j] = bn2.x; bn1[j] = bn2.y;
      unsigned pk = (unsigned)f2bf(h2.x) | ((unsigned)f2bf(h2.y) << 16);
      __hip_atomic_store(hbu + ((((unsigned)(eb + e) << 9) + cb + cp) >> 1), pk,
                         __ATOMIC_RELAXED, __HIP_MEMORY_SCOPE_AGENT);
    }
  }

  unsigned bt = 0;
  unsigned int* myflag = cnt + bid * 16;            // 64B apart
  unsigned int* pollbase = cnt + (g * 8) * 16;

  // double-buffered gi/mask register sets; preload slot A for t=0
  unsigned grA[3], gzA[3], gnA[3];
  unsigned grB[3], gzB[3], gnB[3];
  float mkA[3], mkB[3];
#pragma unroll
  for (int j = 0; j < 3; ++j) {
    int idx = tid + j * 384;
    if (idx < 1024) {
      int e = idx >> 5, cp = (idx & 31) << 1;
      const unsigned short* gp2 = gi + ((size_t)(eb + e) * 1536 + cb + cp);
      grA[j] = *(const unsigned*)gp2;
      gzA[j] = *(const unsigned*)(gp2 + 512);
      gnA[j] = *(const unsigned*)(gp2 + 1024);
      mkA[j] = masks[eb + e];
    }
  }

  // initial barrier: h0 visible group-wide
  __syncthreads();
  bt += 1;
  if (tid == 0)
    __hip_atomic_store(myflag, bt, __ATOMIC_RELAXED, __HIP_MEMORY_SCOPE_AGENT);
  if (tid < 64) {
    unsigned int* fp = pollbase + (lane & 7) * 16;
    int guard = 0;
    for (;;) {
      unsigned v = __hip_atomic_load(fp, __ATOMIC_RELAXED, __HIP_MEMORY_SCOPE_AGENT);
      if (__all(v >= bt)) break;
      __builtin_amdgcn_s_sleep(1);
      if (++guard > (1 << 20)) break;
    }
  }
  __syncthreads();

  for (int u = 0; u < 64; ++u) {
    const int te = 2 * u;
    const int to = 2 * u + 1;
    REC_STEP(te, 0u, 131072u, grA, gzA, gnA, mkA, grB, gzB, gnB, mkB);
    REC_STEP(to, 131072u, 0u, grB, gzB, gnB, mkB, grA, gzA, gnA, mkA);
  }
}
#undef REC_STEP

// ---------------------------------------------------------------------------
// In-place LayerNorm over 65536 rows of 512 (one wave per row).
__global__ __launch_bounds__(256) void ln_kernel(float* __restrict__ out,
                                                 const float* __restrict__ lnw,
                                                 const float* __restrict__ lnb) {
  int row = blockIdx.x * 4 + (threadIdx.x >> 6);
  int lane = threadIdx.x & 63;
  float* p = out + (size_t)row * 512 + lane * 8;
  float4 v0 = *(float4*)p;
  float4 v1 = *(float4*)(p + 4);
  float s = v0.x + v0.y + v0.z + v0.w + v1.x + v1.y + v1.z + v1.w;
  float q = v0.x * v0.x + v0.y * v0.y + v0.z * v0.z + v0.w * v0.w +
            v1.x * v1.x + v1.y * v1.y + v1.z * v1.z + v1.w * v1.w;
#pragma unroll
  for (int m = 1; m < 64; m <<= 1) {
    s += __shfl_xor(s, m, 64);
    q += __shfl_xor(q, m, 64);
  }
  float mean = s * (1.0f / 512.0f);
  float var = q * (1.0f / 512.0f) - mean * mean;
  float rstd = rsqrtf(fmaxf(var, 0.0f) + 1e-5f);
  float4 w0 = *(const float4*)(lnw + lane * 8);
  float4 w1 = *(const float4*)(lnw + lane * 8 + 4);
  float4 b0 = *(const float4*)(lnb + lane * 8);
  float4 b1 = *(const float4*)(lnb + lane * 8 + 4);
  v0.x = (v0.x - mean) * rstd * w0.x + b0.x;
  v0.y = (v0.y - mean) * rstd * w0.y + b0.y;
  v0.z = (v0.z - mean) * rstd * w0.z + b0.z;
  v0.w = (v0.w - mean) * rstd * w0.w + b0.w;
  v1.x = (v1.x - mean) * rstd * w1.x + b1.x;
  v1.y = (v1.y - mean) * rstd * w1.y + b1.y;
  v1.z = (v1.z - mean) * rstd * w1.z + b1.z;
  v1.w = (v1.w - mean) * rstd * w1.w + b1.w;
  *(float4*)p = v0;
  *(float4*)(p + 4) = v1;
}

// ---------------------------------------------------------------------------
extern "C" void kernel_launch(void* const* d_in, const int* in_sizes, int n_in,
                              void* d_out, int out_size, void* d_ws, size_t ws_size,
                              hipStream_t stream) {
  const float* x    = (const float*)d_in[0];
  const float* hxs  = (const float*)d_in[1];
  const float* masks= (const float*)d_in[2];
  const float* wih  = (const float*)d_in[3];
  const float* whh  = (const float*)d_in[4];
  const float* bih  = (const float*)d_in[5];
  const float* bhh  = (const float*)d_in[6];
  const float* lnw  = (const float*)d_in[7];
  const float* lnb  = (const float*)d_in[8];
  float* out = (float*)d_out;
  char* ws = (char*)d_ws;

  unsigned short* gi     = (unsigned short*)ws;
  unsigned short* whh_bf = (unsigned short*)(ws + WHH_OFF);
  unsigned short* hb     = (unsigned short*)(ws + HB_OFF);
  unsigned int*   cnt    = (unsigned int*)(ws + CNT_OFF);
  unsigned short* xbf    = (unsigned short*)(ws + XBF_OFF);
  unsigned short* wih_bf = (unsigned short*)(ws + WIHBF_OFF);
  const int fast = (ws_size >= WS_FAST) ? 1 : 0;

  prep_kernel<<<1024, 256, 0, stream>>>(whh, wih, whh_bf, wih_bf, cnt, fast);
  if (fast) {
    // chunked x2 so xbf (33.5 MB) + gi (201 MB) fits a 256 MiB workspace;
    // stream order serializes xconv -> gemm -> xconv (buffer reuse safe)
    xconv_kernel<<<4096, 256, 0, stream>>>(x, xbf);
    gi_gemm_bf16<<<dim3(256, 12), 256, 0, stream>>>(xbf, wih_bf, bih, bhh, gi, 0);
    xconv_kernel<<<4096, 256, 0, stream>>>(x + (size_t)32768 * 512, xbf);
    gi_gemm_bf16<<<dim3(256, 12), 256, 0, stream>>>(xbf, wih_bf, bih, bhh, gi, 32768);
  } else {
    gi_gemm_f32<<<dim3(512, 12), 256, 0, stream>>>(x, wih, bih, bhh, gi);
  }
  rec_kernel<<<128, 384, 0, stream>>>(hxs, masks, bhh, gi, whh_bf, hb, cnt, out);
  ln_kernel<<<16384, 256, 0, stream>>>(out, lnw, lnb);
}